// Round 1
// baseline (26608.432 us; speedup 1.0000x reference)
//
#include <hip/hip_runtime.h>
#include <hip/hip_bf16.h>

typedef float f32x4 __attribute__((ext_vector_type(4)));
typedef __bf16 bf16x8 __attribute__((ext_vector_type(8)));

#define DEVI static __device__ __forceinline__

DEVI unsigned f2bfu(float f){
  unsigned u = __builtin_bit_cast(unsigned, f);
  return (u + 0x7fffu + ((u >> 16) & 1u)) >> 16;   // RNE f32->bf16
}
DEVI float bf2f(unsigned s){
  return __builtin_bit_cast(float, s << 16);
}
DEVI float sigf(float x){ return 1.f/(1.f + __expf(-x)); }
DEVI float thf(float x){ return 2.f*sigf(2.f*x) - 1.f; }

// ---------------------------------------------------------------------------
// Pack LSTM weights (4 LSTMs) into MFMA B-fragment-linear bf16 layout.
// W_aug is (288 x 1024): rows 0..255 = Whh, rows 256+.. = Wih (x-augmentation), rest 0.
// layout: ((((lstm*8 + w)*9 + kt)*8 + nt)*64 + lane)*8 + j
// value  = W_aug[32*kt + 8*(lane>>4) + j][128*w + 16*nt + (lane&15)]
// ---------------------------------------------------------------------------
__global__ __launch_bounds__(256) void k_pack_lstm(
    const float* __restrict__ encWhh, const float* __restrict__ encWih,
    const float* __restrict__ decWhh, const float* __restrict__ decWih,
    unsigned short* __restrict__ outp)
{
  const int total = 4*8*9*8*64*8;
  for (int e = blockIdx.x*blockDim.x + threadIdx.x; e < total; e += gridDim.x*blockDim.x){
    int j  = e & 7;
    int l  = (e >> 3) & 63;
    int nt = (e >> 9) & 7;
    int r  = e >> 12;          // (lstm*8 + w)*9 + kt
    int kt = r % 9;  r /= 9;
    int w  = r & 7;
    int lstm = r >> 3;
    int k = 32*kt + 8*(l >> 4) + j;
    int n = 128*w + 16*nt + (l & 15);
    float v = 0.f;
    if (lstm < 3){
      if (k < 256)      v = encWhh[(lstm*256 + k)*1024 + n];
      else if (k < 259) v = encWih[(lstm*3 + (k-256))*1024 + n];
    } else {
      if (k < 256)      v = decWhh[k*1024 + n];
      else if (k < 260) v = decWih[(k-256)*1024 + n];
    }
    outp[e] = (unsigned short)f2bfu(v);
  }
}

// ---------------------------------------------------------------------------
// Pack projection weights (K x 256 f32) into fragment-linear bf16.
// layout: (((tn*KT + kt)*8 + nt)*64 + lane)*8 + j ; tn in {0,1} (128-col tiles)
// ---------------------------------------------------------------------------
__global__ __launch_bounds__(256) void k_pack_B(
    const float* __restrict__ W, int KT, unsigned short* __restrict__ outp)
{
  const int total = 2*KT*8*64*8;
  for (int e = blockIdx.x*blockDim.x + threadIdx.x; e < total; e += gridDim.x*blockDim.x){
    int j  = e & 7;
    int l  = (e >> 3) & 63;
    int nt = (e >> 9) & 7;
    int r  = e >> 12;          // tn*KT + kt
    int kt = r % KT;
    int tn = r / KT;
    int k = 32*kt + 8*(l >> 4) + j;
    int n = 128*tn + 16*nt + (l & 15);
    outp[e] = (unsigned short)f2bfu(W[k*256 + n]);
  }
}

// ---------------------------------------------------------------------------
// Projection GEMM: C = A(16384xK) * B(Kx256) + bias, then tanh -> bf16 buffer.
// 128x128 tile, BK=32, 4 waves (2x2), mfma_f32_16x16x32_bf16.
// ---------------------------------------------------------------------------
__global__ __launch_bounds__(256) void k_proj(
    const float* __restrict__ A, const unsigned short* __restrict__ Bp,
    const float* __restrict__ bias, unsigned short* __restrict__ outT, int K)
{
  __shared__ unsigned char sA[8192];
  __shared__ unsigned char sB[8192];
  const int tid = threadIdx.x;
  const int l = tid & 63;
  const int wv = tid >> 6;
  const int wm = wv >> 1, wn = wv & 1;
  const int tm = blockIdx.x, tn = blockIdx.y;
  const int KT = K >> 5;

  f32x4 acc[4][4];
  #pragma unroll
  for (int a = 0; a < 4; ++a)
    #pragma unroll
    for (int cc = 0; cc < 4; ++cc)
      acc[a][cc] = f32x4{0.f,0.f,0.f,0.f};

  const int arow = tid >> 1;
  const float* Ap = A + (size_t)(tm*128 + arow)*K + (tid & 1)*16;
  const uint4* Bsrc = (const uint4*)Bp + (size_t)tn*KT*512 + tid*2;

  for (int kt = 0; kt < KT; ++kt){
    // stage A (f32 -> bf16, swizzled)
    float4 f0 = *(const float4*)(Ap + kt*32);
    float4 f1 = *(const float4*)(Ap + kt*32 + 4);
    float4 f2 = *(const float4*)(Ap + kt*32 + 8);
    float4 f3 = *(const float4*)(Ap + kt*32 + 12);
    uint4 p0, p1;
    p0.x = f2bfu(f0.x) | (f2bfu(f0.y) << 16);
    p0.y = f2bfu(f0.z) | (f2bfu(f0.w) << 16);
    p0.z = f2bfu(f1.x) | (f2bfu(f1.y) << 16);
    p0.w = f2bfu(f1.z) | (f2bfu(f1.w) << 16);
    p1.x = f2bfu(f2.x) | (f2bfu(f2.y) << 16);
    p1.y = f2bfu(f2.z) | (f2bfu(f2.w) << 16);
    p1.z = f2bfu(f3.x) | (f2bfu(f3.y) << 16);
    p1.w = f2bfu(f3.z) | (f2bfu(f3.w) << 16);
    unsigned base = arow*64 + (tid & 1)*32;
    unsigned sw = (arow & 3) << 4;
    *(uint4*)(sA + ((base)      ^ sw)) = p0;
    *(uint4*)(sA + ((base + 16) ^ sw)) = p1;
    // stage B (fragment-linear copy)
    *((uint4*)sB + tid*2)     = Bsrc[kt*512];
    *((uint4*)sB + tid*2 + 1) = Bsrc[kt*512 + 1];
    __syncthreads();

    bf16x8 af[4], bf[4];
    #pragma unroll
    for (int a = 0; a < 4; ++a){
      unsigned row = 64*wm + 16*a + (l & 15);
      unsigned off = (row*64 + 16*(l >> 4)) ^ ((row & 3) << 4);
      af[a] = __builtin_bit_cast(bf16x8, *(const uint4*)(sA + off));
    }
    #pragma unroll
    for (int cc = 0; cc < 4; ++cc){
      unsigned off = ((4*wn + cc)*64 + l)*16;
      bf[cc] = __builtin_bit_cast(bf16x8, *(const uint4*)(sB + off));
    }
    #pragma unroll
    for (int a = 0; a < 4; ++a)
      #pragma unroll
      for (int cc = 0; cc < 4; ++cc)
        acc[a][cc] = __builtin_amdgcn_mfma_f32_16x16x32_bf16(af[a], bf[cc], acc[a][cc], 0, 0, 0);
    __syncthreads();
  }
  // epilogue: + bias, tanh, bf16 store
  #pragma unroll
  for (int cc = 0; cc < 4; ++cc){
    int colg = tn*128 + 64*wn + 16*cc + (l & 15);
    float bs = bias[colg];
    #pragma unroll
    for (int a = 0; a < 4; ++a){
      int rowg = tm*128 + 64*wm + 16*a + 4*(l >> 4);
      #pragma unroll
      for (int r = 0; r < 4; ++r){
        outT[(size_t)(rowg + r)*256 + colg] = (unsigned short)f2bfu(thf(acc[a][cc][r] + bs));
      }
    }
  }
}

// ---------------------------------------------------------------------------
// Attention scalar dots. 7 partial dots -> 6 score fields (6,B,T) f32.
// (att_b/ut_b/uf_b/ua_b cancel in softmax and are skipped — exact.)
// ---------------------------------------------------------------------------
__global__ __launch_bounds__(256) void k_attdot(
    const unsigned short* __restrict__ tT, const unsigned short* __restrict__ tF,
    const unsigned short* __restrict__ tA,
    const float* __restrict__ attW, const float* __restrict__ utW,
    const float* __restrict__ ufW, const float* __restrict__ uaW,
    float* __restrict__ s6)
{
  const int l = threadIdx.x & 63;
  const int wid = (blockIdx.x*blockDim.x + threadIdx.x) >> 6;
  const int nw = (gridDim.x*blockDim.x) >> 6;
  float alo[4], ahi[4], wt[4], wf[4], wa[4];
  #pragma unroll
  for (int q = 0; q < 4; ++q){
    alo[q] = attW[4*l + q];
    ahi[q] = attW[256 + 4*l + q];
    wt[q]  = utW[4*l + q];
    wf[q]  = ufW[4*l + q];
    wa[q]  = uaW[4*l + q];
  }
  for (int r = wid; r < 16384; r += nw){
    uint2 vT = *(const uint2*)(tT + (size_t)r*256 + 4*l);
    uint2 vF = *(const uint2*)(tF + (size_t)r*256 + 4*l);
    uint2 vA = *(const uint2*)(tA + (size_t)r*256 + 4*l);
    float xt[4] = { bf2f(vT.x & 0xffff), bf2f(vT.x >> 16), bf2f(vT.y & 0xffff), bf2f(vT.y >> 16) };
    float xf[4] = { bf2f(vF.x & 0xffff), bf2f(vF.x >> 16), bf2f(vF.y & 0xffff), bf2f(vF.y >> 16) };
    float xa[4] = { bf2f(vA.x & 0xffff), bf2f(vA.x >> 16), bf2f(vA.y & 0xffff), bf2f(vA.y >> 16) };
    float ptlo = 0.f, ptu = 0.f, pflo = 0.f, pfhi = 0.f, pfu = 0.f, pahi = 0.f, pau = 0.f;
    #pragma unroll
    for (int q = 0; q < 4; ++q){
      ptlo += xt[q]*alo[q]; ptu += xt[q]*wt[q];
      pflo += xf[q]*alo[q]; pfhi += xf[q]*ahi[q]; pfu += xf[q]*wf[q];
      pahi += xa[q]*ahi[q]; pau += xa[q]*wa[q];
    }
    #pragma unroll
    for (int s = 1; s < 64; s <<= 1){
      ptlo += __shfl_xor(ptlo, s); ptu  += __shfl_xor(ptu, s);
      pflo += __shfl_xor(pflo, s); pfhi += __shfl_xor(pfhi, s);
      pfu  += __shfl_xor(pfu, s);  pahi += __shfl_xor(pahi, s);
      pau  += __shfl_xor(pau, s);
    }
    if (l == 0){
      int o = r;  // r = b*1024 + t already
      s6[o]             = ptlo + pfhi;   // att1 = pair(tr,fr)
      s6[16384 + o]     = pflo + pahi;   // att2 = pair(fr,ar)
      s6[2*16384 + o]   = ptlo + pahi;   // att3 = pair(tr,ar)
      s6[3*16384 + o]   = ptu;           // uni(tr)
      s6[4*16384 + o]   = pfu;           // uni(fr)
      s6[5*16384 + o]   = pau;           // uni(ar)
    }
  }
}

// ---------------------------------------------------------------------------
// Softmax over T per (field,b), scattered into the reference's scrambled
// (B,T,3) layout: dest[b, idx/3, idx%3] with idx = field_in_triple*1024 + tau.
// ---------------------------------------------------------------------------
__global__ __launch_bounds__(256) void k_smax(
    const float* __restrict__ s6, float* __restrict__ attn_tb, float* __restrict__ encin_tb)
{
  __shared__ float red[4];
  const int f = blockIdx.x >> 4;
  const int b = blockIdx.x & 15;
  const int tid = threadIdx.x;
  const float* row = s6 + f*16384 + b*1024;
  float4 v = *(const float4*)(row + 4*tid);
  float mx = fmaxf(fmaxf(v.x, v.y), fmaxf(v.z, v.w));
  #pragma unroll
  for (int s = 1; s < 64; s <<= 1) mx = fmaxf(mx, __shfl_xor(mx, s));
  if ((tid & 63) == 0) red[tid >> 6] = mx;
  __syncthreads();
  mx = fmaxf(fmaxf(red[0], red[1]), fmaxf(red[2], red[3]));
  float e0 = __expf(v.x - mx), e1 = __expf(v.y - mx), e2 = __expf(v.z - mx), e3 = __expf(v.w - mx);
  float sm = e0 + e1 + e2 + e3;
  #pragma unroll
  for (int s = 1; s < 64; s <<= 1) sm += __shfl_xor(sm, s);
  __syncthreads();
  if ((tid & 63) == 0) red[tid >> 6] = sm;
  __syncthreads();
  sm = red[0] + red[1] + red[2] + red[3];
  float inv = 1.f/sm;
  float e[4] = {e0, e1, e2, e3};
  float* dst = (f < 3) ? attn_tb : encin_tb;
  int ff = (f < 3) ? f : f - 3;
  #pragma unroll
  for (int q = 0; q < 4; ++q){
    int idx = ff*1024 + 4*tid + q;
    int tt = idx/3, kk = idx - 3*tt;
    dst[(tt*16 + b)*3 + kk] = e[q]*inv;
  }
}

// ---------------------------------------------------------------------------
// LSTM recurrence (batched M=16 over MFMA), one workgroup per LSTM.
// K augmented to 288: h rows 0..255, x rows 256.., rest 0.
// 8 waves * 8 n-frags = 1024 gate cols; gates regroup through LDS.
// ---------------------------------------------------------------------------
__global__ __launch_bounds__(512) void k_lstm(
    const unsigned short* __restrict__ packW,
    const float* __restrict__ encin_tb,
    const float* __restrict__ attn_tb,
    const float* __restrict__ enc_out_tb,
    const float* __restrict__ target,
    const float* __restrict__ enc_b,
    const float* __restrict__ dec_b,
    const float* __restrict__ dec_h0,
    const float* __restrict__ dec_c0,
    unsigned short* __restrict__ enc_h,
    unsigned short* __restrict__ dec_h,
    int lstm0)
{
  __shared__ unsigned char hl[16*768];    // bf16 [b][k(0..319)] rows padded to 768B, XOR swizzled
  __shared__ unsigned char gl[16*4160];   // f32 gates [b][1024] stride 1040 f32, XOR swizzled
  const int tid = threadIdx.x;
  const int l = tid & 63;
  const int w = tid >> 6;                 // wave 0..7
  const int b = tid & 15;
  const int jb = tid >> 4;                // 0..31
  const int lstm = lstm0 + blockIdx.x;
  const bool isdec = (lstm == 3);

  float bias[2][4][4];
  const float* bsrc = isdec ? dec_b : (enc_b + lstm*1024);
  #pragma unroll
  for (int h2 = 0; h2 < 2; ++h2)
    #pragma unroll
    for (int g = 0; g < 4; ++g)
      #pragma unroll
      for (int q = 0; q < 4; ++q)
        bias[h2][g][q] = bsrc[g*256 + 4*(jb + 32*h2) + q];

  float c[2][4];
  #pragma unroll
  for (int h2 = 0; h2 < 2; ++h2){
    int j0 = 4*(jb + 32*h2);
    #pragma unroll
    for (int q = 0; q < 4; ++q)
      c[h2][q] = isdec ? dec_c0[j0 + q] : 0.f;
    unsigned p0 = 0, p1 = 0;
    if (isdec){
      p0 = f2bfu(dec_h0[j0])   | (f2bfu(dec_h0[j0+1]) << 16);
      p1 = f2bfu(dec_h0[j0+2]) | (f2bfu(dec_h0[j0+3]) << 16);
    }
    uint2 pk; pk.x = p0; pk.y = p1;
    *(uint2*)(hl + ((b*768 + 2*j0) ^ ((b & 7) << 4))) = pk;
  }
  if (tid < 64){  // zero pad rows k=256..319
    int bb = tid & 15, d = tid >> 4;
    unsigned sw = (bb & 7) << 4;
    unsigned base = bb*768 + 512 + d*32;
    uint4 z; z.x = z.y = z.z = z.w = 0;
    *(uint4*)(hl + ((base)      ^ sw)) = z;
    *(uint4*)(hl + ((base + 16) ^ sw)) = z;
  }
  __syncthreads();
  if (tid < 64){  // x(t=0)
    int bb = tid & 15, d = tid >> 4;
    float xv = 0.f;
    if (isdec){
      if (d >= 1 && d < 4)
        xv = attn_tb[bb*3 + 0] * enc_out_tb[bb*3 + (d - 1)];  // ctx(0): only m=0 term
      // d==0: shifted target at t=0 is the zero pad
    } else {
      if (d < 3) xv = encin_tb[bb*3 + d];
    }
    *(unsigned short*)(hl + ((bb*768 + 512 + 2*d) ^ ((bb & 7) << 4))) = (unsigned short)f2bfu(xv);
  }
  __syncthreads();

  const uint4* wb = (const uint4*)packW + (size_t)(lstm*8 + w)*72*64 + l;
  unsigned short* hout_base = isdec ? dec_h : (enc_h + (size_t)lstm*1024*16*256);

  for (int t = 0; t < 1024; ++t){
    // ---- MFMA phase: gates = [h|x] @ W_aug ----
    bf16x8 af[9];
    #pragma unroll
    for (int kt = 0; kt < 9; ++kt){
      unsigned row = l & 15;
      unsigned off = (row*768 + kt*64 + 16*(l >> 4)) ^ ((row & 7) << 4);
      af[kt] = __builtin_bit_cast(bf16x8, *(const uint4*)(hl + off));
    }
    f32x4 acc[8];
    #pragma unroll
    for (int nt = 0; nt < 8; ++nt) acc[nt] = f32x4{0.f,0.f,0.f,0.f};
    #pragma unroll
    for (int kt = 0; kt < 9; ++kt){
      #pragma unroll
      for (int nt = 0; nt < 8; ++nt){
        bf16x8 bf = __builtin_bit_cast(bf16x8, wb[(kt*8 + nt)*64]);
        acc[nt] = __builtin_amdgcn_mfma_f32_16x16x32_bf16(af[kt], bf, acc[nt], 0, 0, 0);
      }
    }
    #pragma unroll
    for (int nt = 0; nt < 8; ++nt){
      int col = 128*w + 16*nt + (l & 15);
      #pragma unroll
      for (int r = 0; r < 4; ++r){
        int br = 4*(l >> 4) + r;
        *(float*)(gl + (((br*1040 + col) << 2) ^ ((br & 7) << 4))) = acc[nt][r];
      }
    }
    __syncthreads();
    // ---- epilogue: nonlinearity + state update ----
    unsigned sw = (b & 7) << 4;
    #pragma unroll
    for (int h2 = 0; h2 < 2; ++h2){
      int j0 = 4*(jb + 32*h2);
      f32x4 zi = *(const f32x4*)(gl + (((b*1040 +       j0) << 2) ^ sw));
      f32x4 zf = *(const f32x4*)(gl + (((b*1040 + 256 + j0) << 2) ^ sw));
      f32x4 zg = *(const f32x4*)(gl + (((b*1040 + 512 + j0) << 2) ^ sw));
      f32x4 zo = *(const f32x4*)(gl + (((b*1040 + 768 + j0) << 2) ^ sw));
      unsigned hp[4];
      #pragma unroll
      for (int q = 0; q < 4; ++q){
        float vi = sigf(zi[q] + bias[h2][0][q]);
        float vf = sigf(zf[q] + bias[h2][1][q]);
        float vg = thf (zg[q] + bias[h2][2][q]);
        float vo = sigf(zo[q] + bias[h2][3][q]);
        float ccv = vf*c[h2][q] + vi*vg;
        c[h2][q] = ccv;
        hp[q] = f2bfu(vo * thf(ccv));
      }
      uint2 pk; pk.x = hp[0] | (hp[1] << 16); pk.y = hp[2] | (hp[3] << 16);
      *(uint2*)(hl + ((b*768 + 2*j0) ^ sw)) = pk;
      *(uint2*)(hout_base + (size_t)(t*16 + b)*256 + j0) = pk;
    }
    // ---- x(t+1) ----
    if (t < 1023 && tid < 64){
      int bb = tid & 15, d = tid >> 4;
      float xv = 0.f;
      int t1 = t + 1;
      if (isdec){
        if (d == 0) xv = target[bb*1024 + t];   // shifted target
        else if (d < 4){
          int k = d - 1;
          float s = 0.f;
          #pragma unroll
          for (int m = 0; m < 3; ++m){
            if (t1 - m >= 0)
              s += attn_tb[(t1*16 + bb)*3 + m] * enc_out_tb[((t1 - m)*16 + bb)*3 + k];
          }
          xv = s;
        }
      } else {
        if (d < 3) xv = encin_tb[(t1*16 + bb)*3 + d];
      }
      *(unsigned short*)(hl + ((bb*768 + 512 + 2*d) ^ ((bb & 7) << 4))) = (unsigned short)f2bfu(xv);
    }
    __syncthreads();
  }
}

// ---------------------------------------------------------------------------
// enc_out[t,b,k] = enc_h[k,t,b,:] . enc_outW[k,:] + enc_outb[k]
// ---------------------------------------------------------------------------
__global__ __launch_bounds__(256) void k_encout(
    const unsigned short* __restrict__ enc_h, const float* __restrict__ outW,
    const float* __restrict__ outb, float* __restrict__ enc_out_tb)
{
  const int l = threadIdx.x & 63;
  const int wid = (blockIdx.x*blockDim.x + threadIdx.x) >> 6;
  const int nw = (gridDim.x*blockDim.x) >> 6;
  for (int e = wid; e < 3*1024*16; e += nw){
    int k = e >> 14;
    int t = (e >> 4) & 1023;
    int b = e & 15;
    uint2 v = *(const uint2*)(enc_h + ((size_t)(k*1024 + t)*16 + b)*256 + 4*l);
    float p = bf2f(v.x & 0xffff)*outW[k*256 + 4*l]
            + bf2f(v.x >> 16)   *outW[k*256 + 4*l + 1]
            + bf2f(v.y & 0xffff)*outW[k*256 + 4*l + 2]
            + bf2f(v.y >> 16)   *outW[k*256 + 4*l + 3];
    #pragma unroll
    for (int s = 1; s < 64; s <<= 1) p += __shfl_xor(p, s);
    if (l == 0) enc_out_tb[(t*16 + b)*3 + k] = p + outb[k];
  }
}

// ---------------------------------------------------------------------------
// y[b,t] = relu(dec_h[t,b,:] @ W1 + b1) @ W2 + b2
// ---------------------------------------------------------------------------
__global__ __launch_bounds__(256) void k_decout(
    const unsigned short* __restrict__ dec_h, const float* __restrict__ W1,
    const float* __restrict__ b1, const float* __restrict__ W2,
    const float* __restrict__ b2, float* __restrict__ out)
{
  const int l = threadIdx.x & 63;
  const int wid = (blockIdx.x*blockDim.x + threadIdx.x) >> 6;
  const int nw = (gridDim.x*blockDim.x) >> 6;
  const int o = l >> 4, jc = l & 15;
  for (int e = wid; e < 16384; e += nw){
    int t = e >> 4, b = e & 15;
    const unsigned short* hr = dec_h + (size_t)(t*16 + b)*256 + jc*16;
    uint4 v0 = *(const uint4*)hr;
    uint4 v1 = *(const uint4*)(hr + 8);
    unsigned vv[8] = {v0.x, v0.y, v0.z, v0.w, v1.x, v1.y, v1.z, v1.w};
    float p = 0.f;
    #pragma unroll
    for (int q = 0; q < 8; ++q){
      int j = jc*16 + 2*q;
      p += bf2f(vv[q] & 0xffff) * W1[j*4 + o];
      p += bf2f(vv[q] >> 16)    * W1[(j + 1)*4 + o];
    }
    p += __shfl_xor(p, 1); p += __shfl_xor(p, 2);
    p += __shfl_xor(p, 4); p += __shfl_xor(p, 8);
    float v = 0.f;
    if (jc == 0) v = fmaxf(p + b1[o], 0.f) * W2[o];
    v += __shfl_xor(v, 16);
    v += __shfl_xor(v, 32);
    if (l == 0) out[b*1024 + t] = v + b2[0];
  }
}

// ---------------------------------------------------------------------------
extern "C" void kernel_launch(void* const* d_in, const int* in_sizes, int n_in,
                              void* d_out, int out_size, void* d_ws, size_t ws_size,
                              hipStream_t stream)
{
  const float* faceF   = (const float*)d_in[1];
  const float* audioF  = (const float*)d_in[2];
  const float* textF   = (const float*)d_in[3];
  const float* target  = (const float*)d_in[4];
  const float* textW   = (const float*)d_in[5];
  const float* textB   = (const float*)d_in[6];
  const float* faceW   = (const float*)d_in[7];
  const float* faceB   = (const float*)d_in[8];
  const float* audioW  = (const float*)d_in[9];
  const float* audioB  = (const float*)d_in[10];
  const float* attW    = (const float*)d_in[11];
  const float* utW     = (const float*)d_in[13];
  const float* ufW     = (const float*)d_in[15];
  const float* uaW     = (const float*)d_in[17];
  const float* encWih  = (const float*)d_in[19];
  const float* encWhh  = (const float*)d_in[20];
  const float* encB    = (const float*)d_in[21];
  const float* encOutW = (const float*)d_in[22];
  const float* encOutB = (const float*)d_in[23];
  const float* decWih  = (const float*)d_in[24];
  const float* decWhh  = (const float*)d_in[25];
  const float* decB    = (const float*)d_in[26];
  const float* decH0   = (const float*)d_in[27];
  const float* decC0   = (const float*)d_in[28];
  const float* out1W   = (const float*)d_in[29];
  const float* out1B   = (const float*)d_in[30];
  const float* out2W   = (const float*)d_in[31];
  const float* out2B   = (const float*)d_in[32];
  float* out = (float*)d_out;

  char* ws = (char*)d_ws;
  size_t off = 0;
  auto alloc = [&](size_t bytes) -> void* {
    void* p = ws + off;
    off += (bytes + 255) & ~(size_t)255;
    return p;
  };
  unsigned short* packL   = (unsigned short*)alloc(1179648ull*2);
  unsigned short* packT   = (unsigned short*)alloc(196608ull*2);
  unsigned short* packF   = (unsigned short*)alloc(131072ull*2);
  unsigned short* packA   = (unsigned short*)alloc(65536ull*2);
  unsigned short* tanhT   = (unsigned short*)alloc(16384ull*256*2);
  unsigned short* tanhF   = (unsigned short*)alloc(16384ull*256*2);
  unsigned short* tanhA   = (unsigned short*)alloc(16384ull*256*2);
  float*          s6      = (float*)alloc(6ull*16384*4);
  float*          attn_tb = (float*)alloc(49152ull*4);
  float*          encin_tb= (float*)alloc(49152ull*4);
  unsigned short* enc_h   = (unsigned short*)alloc(3ull*1024*16*256*2);
  float*          enc_out_tb = (float*)alloc(49152ull*4);
  unsigned short* dec_h   = (unsigned short*)alloc(1024ull*16*256*2);
  if (off > ws_size) return;  // workspace too small — fail loudly via absmax

  hipLaunchKernelGGL(k_pack_lstm, dim3(512), dim3(256), 0, stream,
                     encWhh, encWih, decWhh, decWih, packL);
  hipLaunchKernelGGL(k_pack_B, dim3(256), dim3(256), 0, stream, textW, 24, packT);
  hipLaunchKernelGGL(k_pack_B, dim3(256), dim3(256), 0, stream, faceW, 16, packF);
  hipLaunchKernelGGL(k_pack_B, dim3(128), dim3(256), 0, stream, audioW, 8, packA);

  hipLaunchKernelGGL(k_proj, dim3(128, 2), dim3(256), 0, stream, textF,  packT, textB,  tanhT, 768);
  hipLaunchKernelGGL(k_proj, dim3(128, 2), dim3(256), 0, stream, faceF,  packF, faceB,  tanhF, 512);
  hipLaunchKernelGGL(k_proj, dim3(128, 2), dim3(256), 0, stream, audioF, packA, audioB, tanhA, 256);

  hipLaunchKernelGGL(k_attdot, dim3(256), dim3(256), 0, stream,
                     tanhT, tanhF, tanhA, attW, utW, ufW, uaW, s6);
  hipLaunchKernelGGL(k_smax, dim3(96), dim3(256), 0, stream, s6, attn_tb, encin_tb);

  hipLaunchKernelGGL(k_lstm, dim3(3), dim3(512), 0, stream,
                     packL, encin_tb, attn_tb, enc_out_tb, target,
                     encB, decB, decH0, decC0, enc_h, dec_h, 0);
  hipLaunchKernelGGL(k_encout, dim3(256), dim3(256), 0, stream,
                     enc_h, encOutW, encOutB, enc_out_tb);
  hipLaunchKernelGGL(k_lstm, dim3(1), dim3(512), 0, stream,
                     packL, encin_tb, attn_tb, enc_out_tb, target,
                     encB, decB, decH0, decC0, enc_h, dec_h, 3);
  hipLaunchKernelGGL(k_decout, dim3(256), dim3(256), 0, stream,
                     dec_h, out1W, out1B, out2W, out2B, out);
}